// Round 4
// baseline (221.740 us; speedup 1.0000x reference)
//
#include <hip/hip_runtime.h>

#define DIM 256
#define T_LEN 4096
#define K_CODES 1024
#define N_TOK 65536
#define NELEM 16777216

// ws layout (32-bit units):
//   [0,1024)              cnh2[k]  packed (bf16_hi | bf16_lo<<16) of 2+0.5|e|^2
//   [1024,3072)           loss partials (2048 f32, written by scatter)
//   [4096,69632)          keys[t]  packed (score_bits & ~1023) | code  (uint)
//   [69632,135168)        x2[t]    exact fp32 |x_t|^2
// d_out[0..131071] floats double as cb_bf16 scratch (512 KB): written by prep,
// read by argmin, dead before scatter overwrites d_out.

typedef __attribute__((ext_vector_type(8))) short bf16x8;
typedef __attribute__((ext_vector_type(16))) float f32x16;

__device__ __forceinline__ unsigned short f2bf(float f) {     // RNE f32->bf16
    unsigned u = __builtin_bit_cast(unsigned, f);
    return (unsigned short)((u + 0x7FFFu + ((u >> 16) & 1u)) >> 16);
}
__device__ __forceinline__ float bf2f(unsigned short h) {
    return __builtin_bit_cast(float, (unsigned)h << 16);
}
__device__ __forceinline__ unsigned f2u(float f) { return __builtin_bit_cast(unsigned, f); }
__device__ __forceinline__ float u2f(unsigned u) { return __builtin_bit_cast(float, u); }
__device__ __forceinline__ unsigned umin2(unsigned a, unsigned b) { return a < b ? a : b; }

union FragU { bf16x8 v; unsigned short u[8]; };

#define GLLOAD(gsrc, lbase)                                                              \
    __builtin_amdgcn_global_load_lds(                                                    \
        (const __attribute__((address_space(1))) unsigned int*)(gsrc),                   \
        (__attribute__((address_space(3))) unsigned int*)(lbase), 16, 0, 0)

// ---------------- prep: cb->bf16, cnh2 split pair, keys init ----------------
__global__ __launch_bounds__(256) void prep(const float* __restrict__ cb,
                                            unsigned short* __restrict__ cbb,
                                            unsigned* __restrict__ cnh2,
                                            unsigned* __restrict__ keys) {
    int k = blockIdx.x * 4 + (threadIdx.x >> 6);
    int lane = threadIdx.x & 63;
    float4 v = *reinterpret_cast<const float4*>(cb + (size_t)k * DIM + lane * 4);
    float s = v.x * v.x + v.y * v.y + v.z * v.z + v.w * v.w;
    #pragma unroll
    for (int off = 32; off; off >>= 1) s += __shfl_down(s, off);
    if (lane == 0) {
        float cn = 2.0f + 0.5f * s;
        unsigned short chi = f2bf(cn);
        unsigned short clo = f2bf(cn - bf2f(chi));
        cnh2[k] = (unsigned)chi | ((unsigned)clo << 16);
    }
    ushort4 o;
    o.x = f2bf(v.x); o.y = f2bf(v.y); o.z = f2bf(v.z); o.w = f2bf(v.w);
    *reinterpret_cast<ushort4*>(cbb + (size_t)k * DIM + lane * 4) = o;
    keys[blockIdx.x * 256 + threadIdx.x] = 0xFFFFFFFFu;
}

// ---------------- argmin via MFMA, K-split + atomicMin merge ----------------
// 512 blocks = 256 token-groups x 2 codebook-halves. 4 waves x 64 tokens/wave.
// Loop has ZERO non-stage VMEM: cn folded into MFMA via (cn_hi,cn_lo) extra frag
// against ones, with negated-x B operands => acc = cn - dot = score directly.
__global__ __launch_bounds__(256, 2) void argmin_mfma(const float* __restrict__ x,
                                                      const unsigned short* __restrict__ cbb,
                                                      const unsigned* __restrict__ cnh2,
                                                      unsigned* __restrict__ keys,
                                                      float* __restrict__ x2arr) {
    __shared__ __align__(16) unsigned short cbuf[2][64 * 256];  // 2 x 32 KB
    __shared__ unsigned cnl[512];                               // 2 KB
    const int tid = threadIdx.x;
    const int w = tid >> 6, lane = tid & 63, hi = lane >> 5, ln31 = lane & 31;
    const int tg = blockIdx.x & 255, kh = blockIdx.x >> 8;      // paired blocks same XCD
    const int tw = tg * 256 + w * 64;
    const int b = tw >> 12, t0 = tw & (T_LEN - 1);
    const int khbase = kh * 512;

    // cnh2 half -> LDS (once)
    cnl[tid] = cnh2[khbase + tid];
    cnl[tid + 256] = cnh2[khbase + 256 + tid];

    // ---- chunk staging: linear LDS dest, pre-swizzled global source ----
    auto stage = [&](int kc, int buf) {
        const char* gc = (const char*)cbb + khbase * 512 + kc * 32768;
        char* lb = (char*)&cbuf[buf][0];
        #pragma unroll
        for (int j = 0; j < 8; ++j) {
            int o = j * 4096 + w * 1024 + lane * 16;
            int so = o ^ (((o >> 9) & 31) << 4);
            GLLOAD(gc + so, lb + j * 4096 + w * 1024);
        }
    };
    stage(0, 0);

    // ---- x fragments, NEGATED, + exact fp32 |x|^2 per (grp, half-channels) ----
    FragU xf[2][16];
    float x2[2] = {0.0f, 0.0f};
    #pragma unroll
    for (int g = 0; g < 2; ++g) {
        const float* xb = x + (size_t)b * DIM * T_LEN + (t0 + g * 32 + ln31);
        #pragma unroll
        for (int cf = 0; cf < 16; ++cf) {
            #pragma unroll
            for (int i = 0; i < 8; ++i) {
                int c = cf * 16 + hi * 8 + i;
                float xv = xb[(size_t)c * T_LEN];
                x2[g] += xv * xv;
                xf[g][cf].u[i] = (unsigned short)(f2bf(xv) ^ 0x8000u);
            }
        }
    }

    FragU onef;                                   // B-const: k=0,1 -> 1.0
    #pragma unroll
    for (int i = 0; i < 8; ++i) onef.u[i] = (hi == 0 && i < 2) ? 0x3F80 : 0;

    unsigned best0 = 0xFFFFFFFFu, best1 = 0xFFFFFFFFu;

    for (int kc = 0; kc < 8; ++kc) {
        const int cur = kc & 1;
        if (kc < 7) {
            stage(kc + 1, cur ^ 1);
            asm volatile("s_waitcnt vmcnt(8)" ::: "memory");
        } else {
            asm volatile("s_waitcnt vmcnt(0)" ::: "memory");
        }
        __syncthreads();

        const char* cbp = (const char*)&cbuf[cur][0];
        #pragma unroll
        for (int ct = 0; ct < 2; ++ct) {
            const int r = ct * 32 + ln31;
            bf16x8 af[16];
            #pragma unroll
            for (int cf = 0; cf < 16; ++cf) {
                int cbyte = cf * 32 + hi * 16;
                af[cf] = *(const bf16x8*)(cbp + r * 512 + (cbyte ^ ((r & 31) << 4)));
            }
            const unsigned d = cnl[kc * 64 + ct * 32 + ln31];
            FragU cfr;
            cfr.u[0] = hi ? (unsigned short)0 : (unsigned short)(d & 0xFFFFu);
            cfr.u[1] = hi ? (unsigned short)0 : (unsigned short)(d >> 16);
            #pragma unroll
            for (int i = 2; i < 8; ++i) cfr.u[i] = 0;

            f32x16 acc0, acc1;
            #pragma unroll
            for (int i = 0; i < 16; ++i) { acc0[i] = 0.0f; acc1[i] = 0.0f; }
            acc0 = __builtin_amdgcn_mfma_f32_32x32x16_bf16(cfr.v, onef.v, acc0, 0, 0, 0);
            acc1 = __builtin_amdgcn_mfma_f32_32x32x16_bf16(cfr.v, onef.v, acc1, 0, 0, 0);
            #pragma unroll
            for (int cf = 0; cf < 16; ++cf) {
                acc0 = __builtin_amdgcn_mfma_f32_32x32x16_bf16(af[cf], xf[0][cf].v, acc0, 0, 0, 0);
                acc1 = __builtin_amdgcn_mfma_f32_32x32x16_bf16(af[cf], xf[1][cf].v, acc1, 0, 0, 0);
            }
            const int kbl = khbase + kc * 64 + ct * 32 + hi * 4;
            #pragma unroll
            for (int rg = 0; rg < 16; ++rg) {
                const unsigned kk = (unsigned)(kbl + (rg & 3) + 8 * (rg >> 2));
                best0 = umin2(best0, (f2u(acc0[rg]) & 0xFFFFFC00u) | kk);
                best1 = umin2(best1, (f2u(acc1[rg]) & 0xFFFFFC00u) | kk);
            }
        }
        __syncthreads();
    }

    // merge hi-halves (disjoint code sets, same tokens)
    best0 = umin2(best0, __shfl_xor(best0, 32));
    best1 = umin2(best1, __shfl_xor(best1, 32));
    const float x2m0 = x2[0] + __shfl_xor(x2[0], 32);
    const float x2m1 = x2[1] + __shfl_xor(x2[1], 32);

    const int tok = tw + hi * 32 + ln31;          // hi=0 -> grp0 token, hi=1 -> grp1 token
    atomicMin(&keys[tok], hi ? best1 : best0);
    if (kh == 0) x2arr[tok] = hi ? x2m1 : x2m0;
}

// ---------------- scatter + fused loss partials ----------------
__global__ __launch_bounds__(256) void scatter(const float* __restrict__ cb,
                                               const unsigned* __restrict__ keys,
                                               const float* __restrict__ x2arr,
                                               float* __restrict__ out,
                                               float* __restrict__ part) {
    __shared__ float xs[DIM][36];
    __shared__ int kk[32];
    const int tid = threadIdx.x;
    const int n0 = blockIdx.x * 32;
    const int b = n0 >> 12, t0 = n0 & (T_LEN - 1);

    float contrib = 0.0f;
    if (tid < 32) {
        const unsigned key = keys[n0 + tid];
        kk[tid] = (int)(key & 1023u);
        // per-token |e - x|^2 = 2*(s-2) + |x|^2,  s = key's truncated score
        contrib = 2.0f * (u2f(key & 0xFFFFFC00u) - 2.0f) + x2arr[n0 + tid];
    }
    __syncthreads();

    {   // phase 1: coalesced row gather (float4) -> LDS transpose
        const int w = tid >> 6, l = tid & 63, tt = l & 31, q0 = l >> 5;
        const float* row = cb + (size_t)kk[tt] * DIM;
        #pragma unroll
        for (int r = 0; r < 8; ++r) {
            const int q = r * 8 + w * 2 + q0;
            const float4 v = *reinterpret_cast<const float4*>(row + q * 4);
            xs[q * 4 + 0][tt] = v.x;
            xs[q * 4 + 1][tt] = v.y;
            xs[q * 4 + 2][tt] = v.z;
            xs[q * 4 + 3][tt] = v.w;
        }
    }
    __syncthreads();

    {   // phase 2: coalesced float2 writes over t
        const int c16 = tid >> 4, th = tid & 15;
        #pragma unroll
        for (int r = 0; r < 16; ++r) {
            const int c = r * 16 + c16;
            const float2 v = *reinterpret_cast<const float2*>(&xs[c][2 * th]);
            *reinterpret_cast<float2*>(&out[(((size_t)b * DIM + c) << 12) + t0 + 2 * th]) = v;
        }
    }

    // loss partial: lanes 0-31 of wave 0 hold contrib, rest 0
    if (tid < 64) {
        float s = contrib;
        #pragma unroll
        for (int off = 32; off; off >>= 1) s += __shfl_down(s, off);
        if (tid == 0) part[blockIdx.x] = s;
    }
}

// ---------------- finalize loss ----------------
__global__ __launch_bounds__(256) void finalize(const float* __restrict__ part,
                                                float* __restrict__ loss_out) {
    double s = 0.0;
    for (int i = threadIdx.x; i < 2048; i += 256) s += (double)part[i];
    #pragma unroll
    for (int off = 32; off; off >>= 1) s += __shfl_down(s, off);
    __shared__ double wsum[4];
    const int lane = threadIdx.x & 63, wv = threadIdx.x >> 6;
    if (lane == 0) wsum[wv] = s;
    __syncthreads();
    if (threadIdx.x == 0)
        *loss_out = (float)(2.0 * (wsum[0] + wsum[1] + wsum[2] + wsum[3]) / (double)NELEM);
}

extern "C" void kernel_launch(void* const* d_in, const int* in_sizes, int n_in,
                              void* d_out, int out_size, void* d_ws, size_t ws_size,
                              hipStream_t stream) {
    const float* x  = (const float*)d_in[0];    // [16,256,4096]
    const float* cb = (const float*)d_in[1];    // [1024,256]
    float* out = (float*)d_out;                 // quant (16777216) + loss (1)
    unsigned* ws = (unsigned*)d_ws;
    unsigned* cnh2 = ws;                        // 1024 u32
    float* part = (float*)(ws + 1024);          // 2048 f32
    unsigned* keys = ws + 4096;                 // 65536 u32
    float* x2arr = (float*)(ws + 4096 + 65536); // 65536 f32
    unsigned short* cbb = (unsigned short*)out; // 512 KB scratch; dead before scatter

    prep<<<K_CODES / 4, 256, 0, stream>>>(cb, cbb, cnh2, keys);
    argmin_mfma<<<512, 256, 0, stream>>>(x, cbb, cnh2, keys, x2arr);
    scatter<<<N_TOK / 32, 256, 0, stream>>>(cb, keys, x2arr, out, part);
    finalize<<<1, 256, 0, stream>>>(part, out + NELEM);
}

// Round 5
// 83.068 us; speedup vs baseline: 2.6694x; 2.6694x over previous
//
#include <hip/hip_runtime.h>

#define DIM 256
#define T_LEN 4096
#define K_CODES 1024
#define N_TOK 65536
#define NELEM 16777216

// ws layout (32-bit units):
//   [0,1024)       cnh2[k]  packed (bf16_hi | bf16_lo<<16) of 2+0.5|e|^2
//   [1024,3072)    scatter loss partials (2048 f32)
//   [3072,3328)    argmin |x|^2 partials (256 f32)
//   [4096,69632)   keys[t]  packed (score_bits & ~1023) | code  (uint)
// d_out[0..131071] floats double as cb_bf16 scratch (512 KB): written by prep,
// read by argmin, dead before scatter overwrites d_out.

typedef __attribute__((ext_vector_type(8))) short bf16x8;
typedef __attribute__((ext_vector_type(16))) float f32x16;

__device__ __forceinline__ unsigned short f2bf(float f) {     // RNE f32->bf16
    unsigned u = __builtin_bit_cast(unsigned, f);
    return (unsigned short)((u + 0x7FFFu + ((u >> 16) & 1u)) >> 16);
}
__device__ __forceinline__ float bf2f(unsigned short h) {
    return __builtin_bit_cast(float, (unsigned)h << 16);
}
__device__ __forceinline__ unsigned f2u(float f) { return __builtin_bit_cast(unsigned, f); }
__device__ __forceinline__ float u2f(unsigned u) { return __builtin_bit_cast(float, u); }
__device__ __forceinline__ unsigned umin2(unsigned a, unsigned b) { return a < b ? a : b; }

union FragU { bf16x8 v; unsigned short u[8]; unsigned w[4]; };

#define GLLOAD(gsrc, lbase)                                                              \
    __builtin_amdgcn_global_load_lds(                                                    \
        (const __attribute__((address_space(1))) unsigned int*)(gsrc),                   \
        (__attribute__((address_space(3))) unsigned int*)(lbase), 16, 0, 0)

// cvt two f32 -> packed bf16 pair, NEGATED (folds the -x the cn-trick needs), RNE.
__device__ __forceinline__ unsigned cvtpk_neg(float a, float b) {
    unsigned r;
    asm("v_cvt_pk_bf16_f32 %0, -%1, -%2" : "=v"(r) : "v"(a), "v"(b));
    return r;
}

// ---------------- prep: cb->bf16, cnh2 split pair ----------------
__global__ __launch_bounds__(256) void prep(const float* __restrict__ cb,
                                            unsigned short* __restrict__ cbb,
                                            unsigned* __restrict__ cnh2) {
    int k = blockIdx.x * 4 + (threadIdx.x >> 6);
    int lane = threadIdx.x & 63;
    float4 v = *reinterpret_cast<const float4*>(cb + (size_t)k * DIM + lane * 4);
    float s = v.x * v.x + v.y * v.y + v.z * v.z + v.w * v.w;
    #pragma unroll
    for (int off = 32; off; off >>= 1) s += __shfl_down(s, off);
    if (lane == 0) {
        float cn = 2.0f + 0.5f * s;
        unsigned short chi = f2bf(cn);
        unsigned short clo = f2bf(cn - bf2f(chi));
        cnh2[k] = (unsigned)chi | ((unsigned)clo << 16);
    }
    ushort4 o;
    o.x = f2bf(v.x); o.y = f2bf(v.y); o.z = f2bf(v.z); o.w = f2bf(v.w);
    *reinterpret_cast<ushort4*>(cbb + (size_t)k * DIM + lane * 4) = o;
}

// ---------------- argmin via MFMA, coalesced x ingest ----------------
// 256 blocks x 4 waves x 64 tokens/wave. x loaded float4-coalesced, transposed
// in-lane (cvt_pk + v_perm) into a [256t][128c] bf16 LDS tile (2 halves through
// cbuf), fragments read once into registers; then 16 codebook chunks double-
// buffered, VMEM-free inner loop (cn folded into MFMA), plain key stores.
__global__ __launch_bounds__(256, 2) void argmin_mfma(const float* __restrict__ x,
                                                      const unsigned short* __restrict__ cbb,
                                                      const unsigned* __restrict__ cnh2,
                                                      unsigned* __restrict__ keys,
                                                      float* __restrict__ part2) {
    __shared__ __align__(16) unsigned short cbuf[2][64 * 256];  // 64 KB (x-tile, then cb dbuf)
    __shared__ unsigned cnl[1024];                              // 4 KB
    __shared__ float wsum[4];
    const int tid = threadIdx.x;
    const int w = tid >> 6, lane = tid & 63, hi = lane >> 5, ln31 = lane & 31;
    const int t0 = blockIdx.x * 256;
    const int b = t0 >> 12, tb = t0 & (T_LEN - 1);

    cnl[tid] = cnh2[tid];
    cnl[tid + 256] = cnh2[tid + 256];
    cnl[tid + 512] = cnh2[tid + 512];
    cnl[tid + 768] = cnh2[tid + 768];

    // ---- x ingest: 2 halves of 128 channels through the 64 KB LDS tile ----
    char* lds = (char*)&cbuf[0][0];
    const float* xb = x + (size_t)b * DIM * T_LEN + tb + 4 * lane;
    const int swz = (lane & 7) << 4;
    FragU xf[2][16];            // NEGATED bf16 x fragments, kept for whole sweep
    float x2s = 0.0f;

    #pragma unroll
    for (int h = 0; h < 2; ++h) {
        #pragma unroll
        for (int ii = 0; ii < 8; ++ii) {
            const int cl = ii * 16 + w * 4;                     // c within half
            const size_t cg = (size_t)(h * 128 + cl) * T_LEN;   // global c row
            const float4 P0 = *reinterpret_cast<const float4*>(xb + cg);
            const float4 P1 = *reinterpret_cast<const float4*>(xb + cg + T_LEN);
            const float4 P2 = *reinterpret_cast<const float4*>(xb + cg + 2 * T_LEN);
            const float4 P3 = *reinterpret_cast<const float4*>(xb + cg + 3 * T_LEN);
            x2s = fmaf(P0.x, P0.x, fmaf(P0.y, P0.y, fmaf(P0.z, P0.z, fmaf(P0.w, P0.w, x2s))));
            x2s = fmaf(P1.x, P1.x, fmaf(P1.y, P1.y, fmaf(P1.z, P1.z, fmaf(P1.w, P1.w, x2s))));
            x2s = fmaf(P2.x, P2.x, fmaf(P2.y, P2.y, fmaf(P2.z, P2.z, fmaf(P2.w, P2.w, x2s))));
            x2s = fmaf(P3.x, P3.x, fmaf(P3.y, P3.y, fmaf(P3.z, P3.z, fmaf(P3.w, P3.w, x2s))));
            // packed bf16 (negated): lo = {t1,t0}, hi = {t3,t2} per c-row
            const unsigned l0 = cvtpk_neg(P0.x, P0.y), h0 = cvtpk_neg(P0.z, P0.w);
            const unsigned l1 = cvtpk_neg(P1.x, P1.y), h1 = cvtpk_neg(P1.z, P1.w);
            const unsigned l2 = cvtpk_neg(P2.x, P2.y), h2 = cvtpk_neg(P2.z, P2.w);
            const unsigned l3 = cvtpk_neg(P3.x, P3.y), h3 = cvtpk_neg(P3.z, P3.w);
            // in-lane 4x4 transpose: q[t][{c01,c23}]
            const unsigned q0a = __builtin_amdgcn_perm(l1, l0, 0x05040100u);
            const unsigned q0b = __builtin_amdgcn_perm(l3, l2, 0x05040100u);
            const unsigned q1a = __builtin_amdgcn_perm(l1, l0, 0x07060302u);
            const unsigned q1b = __builtin_amdgcn_perm(l3, l2, 0x07060302u);
            const unsigned q2a = __builtin_amdgcn_perm(h1, h0, 0x05040100u);
            const unsigned q2b = __builtin_amdgcn_perm(h3, h2, 0x05040100u);
            const unsigned q3a = __builtin_amdgcn_perm(h1, h0, 0x07060302u);
            const unsigned q3b = __builtin_amdgcn_perm(h3, h2, 0x07060302u);
            const int cb2 = cl * 2;
            uint2 u;
            u.x = q0a; u.y = q0b;
            *reinterpret_cast<uint2*>(lds + ((((4 * lane + 0) << 8) + cb2) ^ swz)) = u;
            u.x = q1a; u.y = q1b;
            *reinterpret_cast<uint2*>(lds + ((((4 * lane + 1) << 8) + cb2) ^ swz)) = u;
            u.x = q2a; u.y = q2b;
            *reinterpret_cast<uint2*>(lds + ((((4 * lane + 2) << 8) + cb2) ^ swz)) = u;
            u.x = q3a; u.y = q3b;
            *reinterpret_cast<uint2*>(lds + ((((4 * lane + 3) << 8) + cb2) ^ swz)) = u;
        }
        __syncthreads();
        #pragma unroll
        for (int g = 0; g < 2; ++g) {
            const int tp = w * 64 + g * 32 + ln31;
            #pragma unroll
            for (int cfl = 0; cfl < 8; ++cfl) {
                int ad = (tp << 8) + cfl * 32 + hi * 16;
                ad ^= ((tp >> 2) & 7) << 4;
                xf[g][h * 8 + cfl].v = *reinterpret_cast<const bf16x8*>(lds + ad);
            }
        }
        __syncthreads();
    }

    // ---- codebook chunk staging: linear LDS dest, pre-swizzled global source ----
    auto stage = [&](int kc, int buf) {
        const char* gc = (const char*)cbb + kc * 32768;
        char* lb = (char*)&cbuf[buf][0];
        #pragma unroll
        for (int j = 0; j < 8; ++j) {
            int o = j * 4096 + w * 1024 + lane * 16;
            int so = o ^ (((o >> 9) & 31) << 4);
            GLLOAD(gc + so, lb + j * 4096 + w * 1024);
        }
    };
    stage(0, 0);

    FragU onef;                                   // B-const: k=0,1 -> 1.0
    #pragma unroll
    for (int i = 0; i < 8; ++i) onef.u[i] = (hi == 0 && i < 2) ? 0x3F80 : 0;

    unsigned best0 = 0xFFFFFFFFu, best1 = 0xFFFFFFFFu;

    for (int kc = 0; kc < 16; ++kc) {
        const int cur = kc & 1;
        if (kc < 15) {
            stage(kc + 1, cur ^ 1);
            asm volatile("s_waitcnt vmcnt(8)" ::: "memory");
        } else {
            asm volatile("s_waitcnt vmcnt(0)" ::: "memory");
        }
        __syncthreads();

        const char* cbp = (const char*)&cbuf[cur][0];
        #pragma unroll
        for (int ct = 0; ct < 2; ++ct) {
            const int r = ct * 32 + ln31;
            bf16x8 af[16];
            #pragma unroll
            for (int cf = 0; cf < 16; ++cf) {
                int cbyte = cf * 32 + hi * 16;
                af[cf] = *(const bf16x8*)(cbp + r * 512 + (cbyte ^ ((r & 31) << 4)));
            }
            const unsigned d = cnl[kc * 64 + ct * 32 + ln31];
            FragU cfr;
            cfr.u[0] = hi ? (unsigned short)0 : (unsigned short)(d & 0xFFFFu);
            cfr.u[1] = hi ? (unsigned short)0 : (unsigned short)(d >> 16);
            #pragma unroll
            for (int i = 2; i < 8; ++i) cfr.u[i] = 0;

            f32x16 acc0, acc1;
            #pragma unroll
            for (int i = 0; i < 16; ++i) { acc0[i] = 0.0f; acc1[i] = 0.0f; }
            acc0 = __builtin_amdgcn_mfma_f32_32x32x16_bf16(cfr.v, onef.v, acc0, 0, 0, 0);
            acc1 = __builtin_amdgcn_mfma_f32_32x32x16_bf16(cfr.v, onef.v, acc1, 0, 0, 0);
            #pragma unroll
            for (int cf = 0; cf < 16; ++cf) {
                acc0 = __builtin_amdgcn_mfma_f32_32x32x16_bf16(af[cf], xf[0][cf].v, acc0, 0, 0, 0);
                acc1 = __builtin_amdgcn_mfma_f32_32x32x16_bf16(af[cf], xf[1][cf].v, acc1, 0, 0, 0);
            }
            const int kbl = kc * 64 + ct * 32 + hi * 4;
            #pragma unroll
            for (int rg = 0; rg < 16; ++rg) {
                const unsigned kk = (unsigned)(kbl + (rg & 3) + 8 * (rg >> 2));
                best0 = umin2(best0, (f2u(acc0[rg]) & 0xFFFFFC00u) | kk);
                best1 = umin2(best1, (f2u(acc1[rg]) & 0xFFFFFC00u) | kk);
            }
        }
        __syncthreads();
    }

    // merge hi-halves (disjoint code rows, same token col), plain stores
    best0 = umin2(best0, __shfl_xor(best0, 32));
    best1 = umin2(best1, __shfl_xor(best1, 32));
    const int tw = t0 + w * 64;
    if (hi == 0) keys[tw + ln31] = best0;
    else         keys[tw + 32 + ln31] = best1;

    // |x|^2 block partial
    #pragma unroll
    for (int off = 32; off; off >>= 1) x2s += __shfl_down(x2s, off);
    if (lane == 0) wsum[w] = x2s;
    __syncthreads();
    if (tid == 0) part2[blockIdx.x] = wsum[0] + wsum[1] + wsum[2] + wsum[3];
}

// ---------------- scatter + loss partials from keys ----------------
__global__ __launch_bounds__(256) void scatter(const float* __restrict__ cb,
                                               const unsigned* __restrict__ keys,
                                               float* __restrict__ out,
                                               float* __restrict__ part) {
    __shared__ float xs[DIM][36];
    __shared__ int kk[32];
    const int tid = threadIdx.x;
    const int n0 = blockIdx.x * 32;
    const int b = n0 >> 12, t0 = n0 & (T_LEN - 1);

    float contrib = 0.0f;
    if (tid < 32) {
        const unsigned key = keys[n0 + tid];
        kk[tid] = (int)(key & 1023u);
        contrib = 2.0f * (u2f(key & 0xFFFFFC00u) - 2.0f);   // |e|^2 - 2 dot
    }
    __syncthreads();

    {   // phase 1: coalesced row gather (float4) -> LDS transpose
        const int w = tid >> 6, l = tid & 63, tt = l & 31, q0 = l >> 5;
        const float* row = cb + (size_t)kk[tt] * DIM;
        #pragma unroll
        for (int r = 0; r < 8; ++r) {
            const int q = r * 8 + w * 2 + q0;
            const float4 v = *reinterpret_cast<const float4*>(row + q * 4);
            xs[q * 4 + 0][tt] = v.x;
            xs[q * 4 + 1][tt] = v.y;
            xs[q * 4 + 2][tt] = v.z;
            xs[q * 4 + 3][tt] = v.w;
        }
    }
    __syncthreads();

    {   // phase 2: coalesced float2 writes over t
        const int c16 = tid >> 4, th = tid & 15;
        #pragma unroll
        for (int r = 0; r < 16; ++r) {
            const int c = r * 16 + c16;
            const float2 v = *reinterpret_cast<const float2*>(&xs[c][2 * th]);
            *reinterpret_cast<float2*>(&out[(((size_t)b * DIM + c) << 12) + t0 + 2 * th]) = v;
        }
    }

    if (tid < 64) {
        float s = contrib;
        #pragma unroll
        for (int off = 32; off; off >>= 1) s += __shfl_down(s, off);
        if (tid == 0) part[blockIdx.x] = s;
    }
}

// ---------------- finalize loss ----------------
__global__ __launch_bounds__(256) void finalize(const float* __restrict__ part,
                                                const float* __restrict__ part2,
                                                float* __restrict__ loss_out) {
    double s = 0.0;
    for (int i = threadIdx.x; i < 2048; i += 256) s += (double)part[i];
    s += (double)part2[threadIdx.x];
    #pragma unroll
    for (int off = 32; off; off >>= 1) s += __shfl_down(s, off);
    __shared__ double wsum[4];
    const int lane = threadIdx.x & 63, wv = threadIdx.x >> 6;
    if (lane == 0) wsum[wv] = s;
    __syncthreads();
    if (threadIdx.x == 0)
        *loss_out = (float)(2.0 * (wsum[0] + wsum[1] + wsum[2] + wsum[3]) / (double)NELEM);
}

extern "C" void kernel_launch(void* const* d_in, const int* in_sizes, int n_in,
                              void* d_out, int out_size, void* d_ws, size_t ws_size,
                              hipStream_t stream) {
    const float* x  = (const float*)d_in[0];    // [16,256,4096]
    const float* cb = (const float*)d_in[1];    // [1024,256]
    float* out = (float*)d_out;                 // quant (16777216) + loss (1)
    unsigned* ws = (unsigned*)d_ws;
    unsigned* cnh2 = ws;                        // 1024 u32
    float* part = (float*)(ws + 1024);          // 2048 f32
    float* part2 = (float*)(ws + 3072);         // 256 f32
    unsigned* keys = ws + 4096;                 // 65536 u32
    unsigned short* cbb = (unsigned short*)out; // 512 KB scratch; dead before scatter

    prep<<<K_CODES / 4, 256, 0, stream>>>(cb, cbb, cnh2);
    argmin_mfma<<<N_TOK / 256, 256, 0, stream>>>(x, cbb, cnh2, keys, part2);
    scatter<<<N_TOK / 32, 256, 0, stream>>>(cb, keys, out, part);
    finalize<<<1, 256, 0, stream>>>(part, part2, out + NELEM);
}